// Round 5
// baseline (592.864 us; speedup 1.0000x reference)
//
#include <hip/hip_runtime.h>
#include <hip/hip_bf16.h>
#include <math.h>

// Problem constants (fixed by setup_inputs)
#define BB    4
#define NTOK  16384
#define CIN   128
#define COUT  256
#define HM    256
#define WM    256
#define NP    65536      // HM*WM original points per batch
#define HD    128
#define WD    128
#define HC    64
#define WC    64
#define NS    4096       // HC*WC
#define EPS   1e-6f
#define BNEPS 1e-5f

// CSR segment bases (concatenated target domains)
#define SEG_TOK  (BB * NP)                  // 262144
#define SEG_64   (SEG_TOK + BB * NTOK)      // 327680
#define NSEG     (SEG_64 + BB * NS)         // 344064 = 336 * 1024

typedef __attribute__((ext_vector_type(8))) short bfrag8;
typedef __attribute__((ext_vector_type(4))) float ffrag4;

// ---------------- workspace layout (floats) ----------------
// zeroed block first (one small memset), then non-zeroed scratch
static constexpr size_t BNSUM_OFF  = 0;                                   // 256
static constexpr size_t BNSQ_OFF   = BNSUM_OFF + 256;                     // 256
static constexpr size_t MAXW_OFF   = BNSQ_OFF + 256;                      // 4 (pad 256)
static constexpr size_t CNTS_OFF   = MAXW_OFF + 256;                      // NSEG ints
static constexpr size_t CURS_OFF   = CNTS_OFF + NSEG;                     // NSEG ints
static constexpr size_t ZERO_FLOATS = CURS_OFF + NSEG;
// non-zeroed:
static constexpr size_t YBUF_OFF   = (ZERO_FLOATS + 255) & ~(size_t)255;  // BB*HD*WD*COUT bf16 -> /2 floats
static constexpr size_t XMAPN_OFF  = YBUF_OFF + (size_t)BB * HD * WD * COUT / 2; // BB*NP*CIN bf16 -> /2
static constexpr size_t XBF_OFF    = XMAPN_OFF + (size_t)BB * NP * CIN / 2;  // BB*NTOK*CIN bf16 -> /2
static constexpr size_t TOKB_OFF   = XBF_OFF + (size_t)BB * NTOK * CIN / 2;  // BB*NTOK*COUT bf16 -> /2
static constexpr size_t WFRAG_OFF  = TOKB_OFF + (size_t)BB * NTOK * COUT / 2; // 9*4*16*512 bf16 -> /2
static constexpr size_t SFRAG_OFF  = WFRAG_OFF + (size_t)9 * 4 * 16 * 512 / 2; // 4*16*512 bf16 -> /2
static constexpr size_t WEXP_OFF   = SFRAG_OFF + (size_t)4 * 16 * 512 / 2;  // BB*NTOK
static constexpr size_t AWDT_OFF   = WEXP_OFF + (size_t)BB * NTOK;        // BB*NP
static constexpr size_t ABUF_OFF   = AWDT_OFF + (size_t)BB * NP;          // 256
static constexpr size_t BBUF_OFF   = ABUF_OFF + 256;                      // 256
static constexpr size_t CWA_OFF    = BBUF_OFF + 256;                      // 256
static constexpr size_t C0_OFF     = CWA_OFF + 256;                       // 256
static constexpr size_t CELL256_OFF = C0_OFF + 256;                       // BB*NP ints
static constexpr size_t CELL64_OFF  = CELL256_OFF + (size_t)BB * NP;      // BB*NP ints
static constexpr size_t DEN2_OFF   = CELL64_OFF + (size_t)BB * NP;        // BB*NS
static constexpr size_t STARTS_OFF = DEN2_OFF + (size_t)BB * NS;          // NSEG ints
static constexpr size_t BLKSUM_OFF = STARTS_OFF + NSEG;                   // 512 ints
static constexpr size_t BLKEXCL_OFF = BLKSUM_OFF + 512;                   // 512 ints
static constexpr size_t PIDX_OFF   = BLKEXCL_OFF + 512;                   // 3*BB*NP ints

// ---------------- helpers ----------------

__device__ __forceinline__ unsigned short f2bf(float f) {
    unsigned int u = __float_as_uint(f);
    return (unsigned short)((u + 0x7FFFu + ((u >> 16) & 1u)) >> 16);
}
__device__ __forceinline__ float bf2f(unsigned short u) {
    return __uint_as_float((unsigned int)u << 16);
}

// ---------------- kernels ----------------

// grid cell indices for both grids (RNE via rintf) + CSR histogram, fused
__global__ void k_cellhist(const float* __restrict__ loc, const int* __restrict__ idx_agg,
                           int* __restrict__ cell256, int* __restrict__ cell64,
                           int* __restrict__ cnts) {
    int i = blockIdx.x * 256 + threadIdx.x;   // over BB*NP
    int b = i >> 16;
    float lx = fminf(fmaxf(loc[2 * (size_t)i], -1.f), 1.f);
    float ly = fminf(fmaxf(loc[2 * (size_t)i + 1], -1.f), 1.f);
    int px = (int)rintf(0.5f * (lx + 1.f) * WM - 0.5f);
    px = min(max(px, 0), WM - 1);
    int py = (int)rintf(0.5f * (ly + 1.f) * HM - 0.5f);
    py = min(max(py, 0), HM - 1);
    int c256 = py * WM + px;
    cell256[i] = c256;
    int qx = (int)rintf(0.5f * (lx + 1.f) * WC - 0.5f);
    qx = min(max(qx, 0), WC - 1);
    int qy = (int)rintf(0.5f * (ly + 1.f) * HC - 0.5f);
    qy = min(max(qy, 0), HC - 1);
    int c64 = qy * WC + qx;
    cell64[i] = c64;
    atomicAdd(&cnts[b * NP + c256], 1);
    atomicAdd(&cnts[SEG_TOK + b * NTOK + idx_agg[i]], 1);
    atomicAdd(&cnts[SEG_64 + b * NS + c64], 1);
}

// cast x to bf16 once (random-gather source)
__global__ void k_xcast(const float* __restrict__ x, unsigned short* __restrict__ xbf) {
    size_t i = (size_t)blockIdx.x * 256 + threadIdx.x;  // float4 groups
    float4 v = ((const float4*)x)[i];
    ushort4 o;
    o.x = f2bf(v.x); o.y = f2bf(v.y); o.z = f2bf(v.z); o.w = f2bf(v.w);
    ((ushort4*)xbf)[i] = o;
}

// 2-level exclusive scan over NSEG = 336*1024 counters
__global__ __launch_bounds__(256) void k_scan1(const int* __restrict__ cnts,
                                               int* __restrict__ starts,
                                               int* __restrict__ blksum) {
    int t = threadIdx.x;
    int base = blockIdx.x * 1024 + t * 4;
    int4 v = *(const int4*)(cnts + base);
    int tsum = v.x + v.y + v.z + v.w;
    __shared__ int s[256];
    s[t] = tsum;
    __syncthreads();
    for (int off = 1; off < 256; off <<= 1) {
        int add = (t >= off) ? s[t - off] : 0;
        __syncthreads();
        s[t] += add;
        __syncthreads();
    }
    int excl = s[t] - tsum;
    int4 o;
    o.x = excl; o.y = excl + v.x; o.z = o.y + v.y; o.w = o.z + v.z;
    *(int4*)(starts + base) = o;
    if (t == 255) blksum[blockIdx.x] = s[255];
}

__global__ __launch_bounds__(512) void k_scan2(const int* __restrict__ blksum,
                                               int* __restrict__ blkexcl) {
    int t = threadIdx.x;
    __shared__ int s[512];
    int v = (t < 336) ? blksum[t] : 0;
    s[t] = v;
    __syncthreads();
    for (int off = 1; off < 512; off <<= 1) {
        int add = (t >= off) ? s[t - off] : 0;
        __syncthreads();
        s[t] += add;
        __syncthreads();
    }
    if (t < 336) blkexcl[t] = s[t] - v;
}

// fill CSR pools: map stores resolved token id, tok stores point id, cell64 stores token id
__global__ void k_fill(const int* __restrict__ cell256, const int* __restrict__ idx_agg,
                       const int* __restrict__ cell64, const int* __restrict__ starts,
                       const int* __restrict__ blkexcl, int* __restrict__ curs,
                       int* __restrict__ pidx) {
    int gp = blockIdx.x * 256 + threadIdx.x;  // over BB*NP
    int b = gp >> 16;
    int ia = idx_agg[gp];
    int t1 = b * NP + cell256[gp];
    int p1 = starts[t1] + blkexcl[t1 >> 10] + atomicAdd(&curs[t1], 1);
    pidx[p1] = ia;
    int t2 = SEG_TOK + b * NTOK + ia;
    int p2 = starts[t2] + blkexcl[t2 >> 10] + atomicAdd(&curs[t2], 1);
    pidx[p2] = gp;
    int t3 = SEG_64 + b * NS + cell64[gp];
    int p3 = starts[t3] + blkexcl[t3 >> 10] + atomicAdd(&curs[t3], 1);
    pidx[p3] = ia;
}

// token2map as gather: per map cell, sum bf16 token rows, normalize, write bf16
__global__ __launch_bounds__(256) void k_gather_map(const unsigned short* __restrict__ xbf,
                                                    const int* __restrict__ starts,
                                                    const int* __restrict__ blkexcl,
                                                    const int* __restrict__ cnts,
                                                    const int* __restrict__ pidx,
                                                    unsigned short* __restrict__ xmapn) {
    int tgt = blockIdx.x * 8 + (threadIdx.x >> 5);  // over BB*NP
    int lane = threadIdx.x & 31;                    // 32 lanes x 4ch = 128 ch
    int b = tgt >> 16;
    int start = starts[tgt] + blkexcl[tgt >> 10];
    int cnt = cnts[tgt];
    float4 acc = make_float4(0.f, 0.f, 0.f, 0.f);
    for (int j = 0; j < cnt; ++j) {
        int tk = pidx[start + j];
        ushort4 u = *(const ushort4*)(xbf + ((size_t)b * NTOK + tk) * CIN + lane * 4);
        acc.x += bf2f(u.x); acc.y += bf2f(u.y); acc.z += bf2f(u.z); acc.w += bf2f(u.w);
    }
    float inv = 1.0f / ((float)cnt + EPS);
    ushort4 o;
    o.x = f2bf(acc.x * inv);
    o.y = f2bf(acc.y * inv);
    o.z = f2bf(acc.z * inv);
    o.w = f2bf(acc.w * inv);
    *(ushort4*)(xmapn + (size_t)tgt * CIN + lane * 4) = o;
}

// pre-swizzle conv weights into MFMA 16x16x32 B-fragment lane layout
__global__ void k_wfrag(const float* __restrict__ cw, unsigned short* __restrict__ wfrag) {
    int i = blockIdx.x * 256 + threadIdx.x;  // over 9*4*16*512
    int j = i & 7;
    int lane = (i >> 3) & 63;
    int nt = (i >> 9) & 15;
    int kc = (i >> 13) & 3;
    int khw = i >> 15;
    int c = kc * 32 + ((lane >> 4) << 3) + j;
    int n = nt * 16 + (lane & 15);
    wfrag[i] = f2bf(cw[((size_t)khw * CIN + c) * COUT + n]);
}

// pre-swizzle skip weights (COUT x CIN, row-major) into same B-fragment layout
__global__ void k_sfrag(const float* __restrict__ sw, unsigned short* __restrict__ sfrag) {
    int i = blockIdx.x * 256 + threadIdx.x;  // over 4*16*512
    int j = i & 7;
    int lane = (i >> 3) & 63;
    int nt = (i >> 9) & 15;
    int kc = i >> 13;
    int c = kc * 32 + ((lane >> 4) << 3) + j;
    int n = nt * 16 + (lane & 15);
    sfrag[i] = f2bf(sw[(size_t)n * CIN + c]);
}

// 3x3 stride-2 pad-1 conv as implicit GEMM on bf16 MFMA 16x16x32; bf16 output.
__global__ __launch_bounds__(256) void k_convmf(const unsigned short* __restrict__ xmapn,
                                                const unsigned short* __restrict__ wfrag,
                                                const float* __restrict__ cb,
                                                unsigned short* __restrict__ y) {
    int bz = blockIdx.x;
    int ow0 = (bz & 1) * 64;
    int oh = (bz >> 1) & (HD - 1);
    int b = bz >> 8;
    int tid = threadIdx.x;
    int w = tid >> 6, lane = tid & 63;
    int n0 = w * 64;

    __shared__ unsigned short s_even[65 * 136];
    __shared__ unsigned short s_odd[64 * 136];

    ffrag4 acc[4][4];
#pragma unroll
    for (int mt = 0; mt < 4; ++mt)
#pragma unroll
        for (int nt = 0; nt < 4; ++nt) {
            ffrag4 z = {0.f, 0.f, 0.f, 0.f};
            acc[mt][nt] = z;
        }

    int iw0 = 2 * ow0 - 1;
    int lm = lane & 15;
    int lq = lane >> 4;
    int cbase = lq << 3;

    for (int kh = 0; kh < 3; ++kh) {
        int ih = 2 * oh - 1 + kh;
        __syncthreads();
        {
            const unsigned short* rowb =
                xmapn + ((size_t)b * NP + (size_t)ih * WM) * CIN;
            bool ihok = (ih >= 0 && ih < HM);
            for (int idx = tid; idx < 129 * 16; idx += 256) {
                int pix = idx >> 4;
                int c8 = (idx & 15) * 8;
                int iw = iw0 + pix;
                uint4 v = make_uint4(0u, 0u, 0u, 0u);
                if (ihok && iw >= 0 && iw < WM)
                    v = *(const uint4*)(rowb + (size_t)iw * CIN + c8);
                unsigned short* dst = (pix & 1)
                    ? &s_odd[(size_t)((pix - 1) >> 1) * 136 + c8]
                    : &s_even[(size_t)(pix >> 1) * 136 + c8];
                *(uint4*)dst = v;
            }
        }
        __syncthreads();
#pragma unroll
        for (int kw = 0; kw < 3; ++kw) {
            int khw = kh * 3 + kw;
#pragma unroll
            for (int kc = 0; kc < 4; ++kc) {
                int c = kc * 32 + cbase;
                bfrag8 af[4];
#pragma unroll
                for (int mt = 0; mt < 4; ++mt) {
                    int m = mt * 16 + lm;
                    const unsigned short* src;
                    if (kw == 1)      src = &s_odd[(size_t)m * 136 + c];
                    else if (kw == 0) src = &s_even[(size_t)m * 136 + c];
                    else              src = &s_even[(size_t)(m + 1) * 136 + c];
                    af[mt] = *(const bfrag8*)(const void*)src;
                }
                const unsigned short* wb =
                    wfrag + ((size_t)((khw * 4 + kc) * 16) + w * 4) * 512 + lane * 8;
#pragma unroll
                for (int nt = 0; nt < 4; ++nt) {
                    bfrag8 bf = *(const bfrag8*)(const void*)(wb + (size_t)nt * 512);
#pragma unroll
                    for (int mt = 0; mt < 4; ++mt)
                        acc[mt][nt] = __builtin_amdgcn_mfma_f32_16x16x32_bf16(
                            af[mt], bf, acc[mt][nt], 0, 0, 0);
                }
            }
        }
    }

    unsigned short* yb = y + (((size_t)b * HD + oh) * WD + ow0) * COUT;
#pragma unroll
    for (int nt = 0; nt < 4; ++nt) {
        int n = n0 + nt * 16 + lm;
        float bias = cb[n];
#pragma unroll
        for (int mt = 0; mt < 4; ++mt) {
#pragma unroll
            for (int r = 0; r < 4; ++r) {
                int m = mt * 16 + lq * 4 + r;
                yb[(size_t)m * COUT + n] = f2bf(acc[mt][nt][r] + bias);
            }
        }
    }
}

// Fused map2token gather + skip MFMA + BN stats.
// Block = 64 tokens, 4 waves. Phase 1: wave w gathers tokens [w*16, w*16+16)
// (64 lanes x 4ch bilinear), writes num/(den+eps) bf16 to LDS. Phase 2: skip
// GEMM x @ skip_w^T via MFMA (A-fragments direct from global xbf, L1-resident
// tile). Epilogue: tok = LDS num + acc, written once; per-channel BN partial
// sums reduced across quads then one atomic set per wave.
__global__ __launch_bounds__(256) void k_gtokmf(const unsigned short* __restrict__ y,
                                                const float* __restrict__ loc,
                                                const float* __restrict__ aggw,
                                                const unsigned short* __restrict__ xbf,
                                                const unsigned short* __restrict__ sfrag,
                                                const int* __restrict__ starts,
                                                const int* __restrict__ blkexcl,
                                                const int* __restrict__ cnts,
                                                const int* __restrict__ pidx,
                                                float* __restrict__ tok,
                                                float* __restrict__ bnsum,
                                                float* __restrict__ bnsq) {
    int t0 = blockIdx.x * 64;     // grid = BB*NTOK/64
    int tid = threadIdx.x;
    int w = tid >> 6, lane = tid & 63;
    __shared__ unsigned short s_num[64 * 264];   // bf16 num/(den+eps), padded rows

    // ---- phase 1: gather 16 tokens for this wave ----
    for (int i = 0; i < 16; ++i) {
        int row = w * 16 + i;
        int tl = t0 + row;
        int b = tl >> 14;
        int tgt = SEG_TOK + tl;
        int start = starts[tgt] + blkexcl[tgt >> 10];
        int cnt = cnts[tgt];
        const unsigned short* ybase = y + (size_t)b * (HD * WD * COUT);
        float4 num = make_float4(0.f, 0.f, 0.f, 0.f);
        float den = 0.f;
        for (int j = 0; j < cnt; ++j) {
            int gp = pidx[start + j];
            float lx = fminf(fmaxf(loc[2 * (size_t)gp], -1.f), 1.f);
            float ly = fminf(fmaxf(loc[2 * (size_t)gp + 1], -1.f), 1.f);
            float fx = fminf(fmaxf(0.5f * (lx + 1.f) * WD - 0.5f, 0.f), (float)(WD - 1));
            float fy = fminf(fmaxf(0.5f * (ly + 1.f) * HD - 0.5f, 0.f), (float)(HD - 1));
            float x0f = floorf(fx), y0f = floorf(fy);
            float wx = fx - x0f, wy = fy - y0f;
            int x0 = (int)x0f, y0 = (int)y0f;
            int x1 = min(x0 + 1, WD - 1), y1 = min(y0 + 1, HD - 1);
            ushort4 u00 = *(const ushort4*)(ybase + ((size_t)y0 * WD + x0) * COUT + lane * 4);
            ushort4 u01 = *(const ushort4*)(ybase + ((size_t)y0 * WD + x1) * COUT + lane * 4);
            ushort4 u10 = *(const ushort4*)(ybase + ((size_t)y1 * WD + x0) * COUT + lane * 4);
            ushort4 u11 = *(const ushort4*)(ybase + ((size_t)y1 * WD + x1) * COUT + lane * 4);
            float w00 = (1.f - wx) * (1.f - wy), w01 = wx * (1.f - wy);
            float w10 = (1.f - wx) * wy, w11 = wx * wy;
            float aw = aggw[gp];
            num.x += (w00 * bf2f(u00.x) + w01 * bf2f(u01.x) + w10 * bf2f(u10.x) + w11 * bf2f(u11.x)) * aw;
            num.y += (w00 * bf2f(u00.y) + w01 * bf2f(u01.y) + w10 * bf2f(u10.y) + w11 * bf2f(u11.y)) * aw;
            num.z += (w00 * bf2f(u00.z) + w01 * bf2f(u01.z) + w10 * bf2f(u10.z) + w11 * bf2f(u11.z)) * aw;
            num.w += (w00 * bf2f(u00.w) + w01 * bf2f(u01.w) + w10 * bf2f(u10.w) + w11 * bf2f(u11.w)) * aw;
            den += aw;
        }
        float inv = 1.f / (den + EPS);
        ushort4 o;
        o.x = f2bf(num.x * inv);
        o.y = f2bf(num.y * inv);
        o.z = f2bf(num.z * inv);
        o.w = f2bf(num.w * inv);
        *(ushort4*)&s_num[(size_t)row * 264 + lane * 4] = o;
    }
    __syncthreads();

    // ---- phase 2: skip MFMA ----
    int lm = lane & 15, lq = lane >> 4;
    int n0 = w * 64;
    ffrag4 acc[4][4];
#pragma unroll
    for (int mt = 0; mt < 4; ++mt)
#pragma unroll
        for (int nt = 0; nt < 4; ++nt) {
            ffrag4 z = {0.f, 0.f, 0.f, 0.f};
            acc[mt][nt] = z;
        }
#pragma unroll
    for (int kc = 0; kc < 4; ++kc) {
        bfrag8 af[4];
#pragma unroll
        for (int mt = 0; mt < 4; ++mt)
            af[mt] = *(const bfrag8*)(const void*)(xbf +
                     (size_t)(t0 + mt * 16 + lm) * CIN + kc * 32 + lq * 8);
        const unsigned short* sb = sfrag + ((size_t)(kc * 16) + w * 4) * 512 + lane * 8;
#pragma unroll
        for (int nt = 0; nt < 4; ++nt) {
            bfrag8 bf = *(const bfrag8*)(const void*)(sb + (size_t)nt * 512);
#pragma unroll
            for (int mt = 0; mt < 4; ++mt)
                acc[mt][nt] = __builtin_amdgcn_mfma_f32_16x16x32_bf16(
                    af[mt], bf, acc[mt][nt], 0, 0, 0);
        }
    }

    // ---- epilogue: tok = num + skip; BN partial sums ----
    float bsum[4] = {0.f, 0.f, 0.f, 0.f};
    float bsq[4] = {0.f, 0.f, 0.f, 0.f};
#pragma unroll
    for (int mt = 0; mt < 4; ++mt) {
#pragma unroll
        for (int r = 0; r < 4; ++r) {
            int row = mt * 16 + lq * 4 + r;
            int tkn = t0 + row;
#pragma unroll
            for (int nt = 0; nt < 4; ++nt) {
                int n = n0 + nt * 16 + lm;
                float v = bf2f(s_num[(size_t)row * 264 + n]) + acc[mt][nt][r];
                tok[(size_t)tkn * COUT + n] = v;
                bsum[nt] += v;
                bsq[nt] = fmaf(v, v, bsq[nt]);
            }
        }
    }
#pragma unroll
    for (int nt = 0; nt < 4; ++nt) {
        bsum[nt] += __shfl_down(bsum[nt], 32);
        bsq[nt] += __shfl_down(bsq[nt], 32);
        bsum[nt] += __shfl_down(bsum[nt], 16);
        bsq[nt] += __shfl_down(bsq[nt], 16);
    }
    if (lq == 0) {
#pragma unroll
        for (int nt = 0; nt < 4; ++nt) {
            int n = n0 + nt * 16 + lm;
            atomicAdd(&bnsum[n], bsum[nt]);
            atomicAdd(&bnsq[n], bsq[nt]);
        }
    }
}

// per-channel BN affine: a=gamma/sqrt(var+eps), bb=beta-mu*a; fold conf head
__global__ void k_bnparams(const float* __restrict__ bnsum, const float* __restrict__ bnsq,
                           const float* __restrict__ gamma, const float* __restrict__ beta,
                           const float* __restrict__ confw, const float* __restrict__ confb,
                           float* __restrict__ abuf, float* __restrict__ bbuf,
                           float* __restrict__ cwa, float* __restrict__ c0) {
    int k = threadIdx.x;
    const float cntv = (float)(BB * NTOK);
    float mu = bnsum[k] / cntv;
    float var = bnsq[k] / cntv - mu * mu;
    float a = gamma[k] * rsqrtf(var + BNEPS);
    float bbv = beta[k] - mu * a;
    abuf[k] = a;
    bbuf[k] = bbv;
    float cw = confw[k];
    cwa[k] = a * cw;
    __shared__ float red[256];
    red[k] = bbv * cw;
    __syncthreads();
    for (int s = 128; s > 0; s >>= 1) {
        if (k < s) red[k] += red[k + s];
        __syncthreads();
    }
    if (k == 0) c0[0] = red[0] + confb[0];
}

// conf = dot(tok, cwa) + c0; emit tokn bf16 (tokb), exp(conf) (wexp),
// and relu(tokn) in place over tok (out_x region)
__global__ void k_confrelu(float* __restrict__ tok, const float* __restrict__ cwa,
                           const float* __restrict__ c0v, const float* __restrict__ abuf,
                           const float* __restrict__ bbuf, float* __restrict__ conf_out,
                           unsigned short* __restrict__ tokb, float* __restrict__ wexp) {
    int tid = threadIdx.x;
    int tkn = blockIdx.x * 16 + (tid >> 4);
    int kc = (tid & 15) * 16;
    float* row = tok + (size_t)tkn * COUT + kc;
    unsigned short* tb = tokb + (size_t)tkn * COUT + kc;
    float s = 0.f;
#pragma unroll
    for (int i = 0; i < 16; i += 4) {
        float4 v = *(const float4*)(row + i);
        float4 w = *(const float4*)(cwa + kc + i);
        float4 a = *(const float4*)(abuf + kc + i);
        float4 bb = *(const float4*)(bbuf + kc + i);
        s += v.x * w.x + v.y * w.y + v.z * w.z + v.w * w.w;
        float4 tn;
        tn.x = fmaf(a.x, v.x, bb.x);
        tn.y = fmaf(a.y, v.y, bb.y);
        tn.z = fmaf(a.z, v.z, bb.z);
        tn.w = fmaf(a.w, v.w, bb.w);
        ushort4 o;
        o.x = f2bf(tn.x); o.y = f2bf(tn.y); o.z = f2bf(tn.z); o.w = f2bf(tn.w);
        *(ushort4*)(tb + i) = o;
        float4 rl;
        rl.x = fmaxf(tn.x, 0.f); rl.y = fmaxf(tn.y, 0.f);
        rl.z = fmaxf(tn.z, 0.f); rl.w = fmaxf(tn.w, 0.f);
        *(float4*)(row + i) = rl;
    }
    for (int off = 8; off > 0; off >>= 1) s += __shfl_down(s, off, 16);
    if ((tid & 15) == 0) {
        float cv = s + c0v[0];
        conf_out[tkn] = cv;
        wexp[tkn] = expf(cv);
    }
}

// cluster as gather over bf16 tokn rows + precomputed exp weights; fused relu epilogue
__global__ __launch_bounds__(256) void k_gather_cluster(const unsigned short* __restrict__ tokb,
                                                        const float* __restrict__ wexp,
                                                        const int* __restrict__ starts,
                                                        const int* __restrict__ blkexcl,
                                                        const int* __restrict__ cnts,
                                                        const int* __restrict__ pidx,
                                                        float* __restrict__ xdown,
                                                        float* __restrict__ den2) {
    int wv = threadIdx.x >> 6, lane = threadIdx.x & 63;  // 64 lanes x 4ch = 256 ch
    int tl = blockIdx.x * 4 + wv;                        // over BB*NS
    int b = tl >> 12;
    int tgt = SEG_64 + tl;
    int start = starts[tgt] + blkexcl[tgt >> 10];
    int cnt = cnts[tgt];
    float4 num = make_float4(0.f, 0.f, 0.f, 0.f);
    float den = 0.f;
    for (int j = 0; j < cnt; ++j) {
        int ia = pidx[start + j];
        float w = wexp[(size_t)b * NTOK + ia];
        ushort4 u = *(const ushort4*)(tokb + ((size_t)b * NTOK + ia) * COUT + lane * 4);
        num.x = fmaf(bf2f(u.x), w, num.x);
        num.y = fmaf(bf2f(u.y), w, num.y);
        num.z = fmaf(bf2f(u.z), w, num.z);
        num.w = fmaf(bf2f(u.w), w, num.w);
        den += w;
    }
    float inv = 1.f / (den + EPS);
    float4 o;
    o.x = fmaxf(num.x * inv, 0.f);
    o.y = fmaxf(num.y * inv, 0.f);
    o.z = fmaxf(num.z * inv, 0.f);
    o.w = fmaxf(num.w * inv, 0.f);
    *(float4*)(xdown + (size_t)tl * COUT + lane * 4) = o;
    if (lane == 0) den2[tl] = den;
}

// agg_weight_down numerator + per-batch max (positive floats -> uint atomicMax)
__global__ void k_awd1(const float* __restrict__ wexp, const float* __restrict__ den2,
                       const int* __restrict__ idx_agg, const int* __restrict__ cell64,
                       const float* __restrict__ aggw, float* __restrict__ awdt,
                       float* __restrict__ idx_out_f, unsigned int* __restrict__ maxw) {
    int b = blockIdx.x >> 6;
    int chunk = blockIdx.x & 63;
    int base = b * NP + chunk * 1024;
    float lmax = 0.f;
    for (int t = threadIdx.x; t < 1024; t += 256) {
        int gp = base + t;
        int ia = idx_agg[gp];
        int cell = cell64[gp];
        float w = wexp[(size_t)b * NTOK + ia];
        float wt = w / (den2[(size_t)b * NS + cell] + EPS);
        float tv = aggw[gp] * wt;
        awdt[gp] = tv;
        idx_out_f[gp] = (float)cell;
        lmax = fmaxf(lmax, tv);
    }
    __shared__ float red[256];
    red[threadIdx.x] = lmax;
    __syncthreads();
    for (int s = 128; s > 0; s >>= 1) {
        if (threadIdx.x < s) red[threadIdx.x] = fmaxf(red[threadIdx.x], red[threadIdx.x + s]);
        __syncthreads();
    }
    if (threadIdx.x == 0) atomicMax(maxw + b, __float_as_uint(red[0]));
}

__global__ void k_awd2(const float* __restrict__ awdt, const unsigned int* __restrict__ maxw,
                       float* __restrict__ awd_out) {
    int i = blockIdx.x * 256 + threadIdx.x;  // over BB*NP
    int b = i >> 16;
    awd_out[i] = awdt[i] / __uint_as_float(maxw[b]);
}

extern "C" void kernel_launch(void* const* d_in, const int* in_sizes, int n_in,
                              void* d_out, int out_size, void* d_ws, size_t ws_size,
                              hipStream_t stream) {
    const float* x        = (const float*)d_in[0];
    const float* loc      = (const float*)d_in[1];
    const int*   idx_agg  = (const int*)d_in[2];
    const float* aggw     = (const float*)d_in[3];
    const float* conv_w   = (const float*)d_in[4];
    const float* conv_b   = (const float*)d_in[5];
    const float* skip_w   = (const float*)d_in[6];
    const float* bn_gamma = (const float*)d_in[7];
    const float* bn_beta  = (const float*)d_in[8];
    const float* conf_w   = (const float*)d_in[9];
    const float* conf_b   = (const float*)d_in[10];

    float* ws      = (float*)d_ws;
    float* bnsum   = ws + BNSUM_OFF;
    float* bnsq    = ws + BNSQ_OFF;
    unsigned int* maxw = (unsigned int*)(ws + MAXW_OFF);
    int*   cnts    = (int*)(ws + CNTS_OFF);
    int*   curs    = (int*)(ws + CURS_OFF);
    unsigned short* ybuf  = (unsigned short*)(ws + YBUF_OFF);
    unsigned short* xmapn = (unsigned short*)(ws + XMAPN_OFF);
    unsigned short* xbf   = (unsigned short*)(ws + XBF_OFF);
    unsigned short* tokb  = (unsigned short*)(ws + TOKB_OFF);
    unsigned short* wfrag = (unsigned short*)(ws + WFRAG_OFF);
    unsigned short* sfrag = (unsigned short*)(ws + SFRAG_OFF);
    float* wexp    = ws + WEXP_OFF;
    float* awdt    = ws + AWDT_OFF;
    float* abuf    = ws + ABUF_OFF;
    float* bbuf    = ws + BBUF_OFF;
    float* cwa     = ws + CWA_OFF;
    float* c0      = ws + C0_OFF;
    int*   cell256 = (int*)(ws + CELL256_OFF);
    int*   cell64  = (int*)(ws + CELL64_OFF);
    float* den2    = ws + DEN2_OFF;
    int*   starts  = (int*)(ws + STARTS_OFF);
    int*   blksum  = (int*)(ws + BLKSUM_OFF);
    int*   blkexcl = (int*)(ws + BLKEXCL_OFF);
    int*   pidx    = (int*)(ws + PIDX_OFF);

    float* out       = (float*)d_out;
    float* out_xdown = out;                                    // [4,4096,256]
    float* out_x     = out + (size_t)BB * NS * COUT;           // [4,16384,256] (tok -> relu(tokn))
    float* out_conf  = out_x + (size_t)BB * NTOK * COUT;       // [4,16384,1]
    float* out_awd   = out_conf + (size_t)BB * NTOK;           // [4,65536,1]
    float* out_idx   = out_awd + (size_t)BB * NP;              // [4,65536] written as float

    // zero the small accumulator region (ws is poisoned 0xAA every call)
    hipMemsetAsync(d_ws, 0, ZERO_FLOATS * sizeof(float), stream);

    k_xcast<<<BB * NTOK * CIN / 4 / 256, 256, 0, stream>>>(x, xbf);
    k_wfrag<<<9 * 4 * 16 * 512 / 256, 256, 0, stream>>>(conv_w, wfrag);
    k_sfrag<<<4 * 16 * 512 / 256, 256, 0, stream>>>(skip_w, sfrag);
    k_cellhist<<<BB * NP / 256, 256, 0, stream>>>(loc, idx_agg, cell256, cell64, cnts);
    k_scan1<<<NSEG / 1024, 256, 0, stream>>>(cnts, starts, blksum);
    k_scan2<<<1, 512, 0, stream>>>(blksum, blkexcl);
    k_fill<<<BB * NP / 256, 256, 0, stream>>>(cell256, idx_agg, cell64, starts,
                                              blkexcl, curs, pidx);
    k_gather_map<<<BB * NP / 8, 256, 0, stream>>>(xbf, starts, blkexcl, cnts, pidx, xmapn);
    k_convmf<<<BB * HD * 2, 256, 0, stream>>>(xmapn, wfrag, conv_b, ybuf);
    k_gtokmf<<<BB * NTOK / 64, 256, 0, stream>>>(ybuf, loc, aggw, xbf, sfrag,
                                                 starts, blkexcl, cnts, pidx,
                                                 out_x, bnsum, bnsq);
    k_bnparams<<<1, 256, 0, stream>>>(bnsum, bnsq, bn_gamma, bn_beta, conf_w, conf_b,
                                      abuf, bbuf, cwa, c0);
    k_confrelu<<<BB * NTOK / 16, 256, 0, stream>>>(out_x, cwa, c0, abuf, bbuf,
                                                   out_conf, tokb, wexp);
    k_gather_cluster<<<BB * NS / 4, 256, 0, stream>>>(tokb, wexp, starts, blkexcl,
                                                      cnts, pidx, out_xdown, den2);
    k_awd1<<<BB * 64, 256, 0, stream>>>(wexp, den2, idx_agg, cell64, aggw,
                                        awdt, out_idx, maxw);
    k_awd2<<<BB * NP / 256, 256, 0, stream>>>(awdt, maxw, out_awd);
}

// Round 6
// 549.089 us; speedup vs baseline: 1.0797x; 1.0797x over previous
//
#include <hip/hip_runtime.h>
#include <hip/hip_bf16.h>
#include <math.h>

// Problem constants (fixed by setup_inputs)
#define BB    4
#define NTOK  16384
#define CIN   128
#define COUT  256
#define HM    256
#define WM    256
#define NP    65536      // HM*WM original points per batch
#define HD    128
#define WD    128
#define HC    64
#define WC    64
#define NS    4096       // HC*WC
#define EPS   1e-6f
#define BNEPS 1e-5f

// CSR segment bases (concatenated target domains)
#define SEG_TOK  (BB * NP)                  // 262144
#define SEG_64   (SEG_TOK + BB * NTOK)      // 327680
#define NSEG     (SEG_64 + BB * NS)         // 344064 = 336 * 1024

typedef __attribute__((ext_vector_type(8))) short bfrag8;
typedef __attribute__((ext_vector_type(4))) float ffrag4;

// ---------------- workspace layout (floats) ----------------
// zeroed block first (one small memset), then non-zeroed scratch
static constexpr size_t BNSUM_OFF  = 0;                                   // 256
static constexpr size_t BNSQ_OFF   = BNSUM_OFF + 256;                     // 256
static constexpr size_t MAXW_OFF   = BNSQ_OFF + 256;                      // 4 (pad 256)
static constexpr size_t CNTS_OFF   = MAXW_OFF + 256;                      // NSEG ints
static constexpr size_t CURS_OFF   = CNTS_OFF + NSEG;                     // NSEG ints
static constexpr size_t ZERO_FLOATS = CURS_OFF + NSEG;
// non-zeroed:
static constexpr size_t YBUF_OFF   = (ZERO_FLOATS + 255) & ~(size_t)255;  // BB*HD*WD*COUT bf16 -> /2 floats
static constexpr size_t XMAPN_OFF  = YBUF_OFF + (size_t)BB * HD * WD * COUT / 2; // BB*NP*CIN bf16 -> /2
static constexpr size_t XBF_OFF    = XMAPN_OFF + (size_t)BB * NP * CIN / 2;  // BB*NTOK*CIN bf16 -> /2
static constexpr size_t TOKB_OFF   = XBF_OFF + (size_t)BB * NTOK * CIN / 2;  // BB*NTOK*COUT bf16 -> /2
static constexpr size_t WFRAG_OFF  = TOKB_OFF + (size_t)BB * NTOK * COUT / 2; // 9*4*16*512 bf16 -> /2
static constexpr size_t SFRAG_OFF  = WFRAG_OFF + (size_t)9 * 4 * 16 * 512 / 2; // 4*16*512 bf16 -> /2
static constexpr size_t WEXP_OFF   = SFRAG_OFF + (size_t)4 * 16 * 512 / 2;  // BB*NTOK
static constexpr size_t AWDT_OFF   = WEXP_OFF + (size_t)BB * NTOK;        // BB*NP
static constexpr size_t ABUF_OFF   = AWDT_OFF + (size_t)BB * NP;          // 256
static constexpr size_t BBUF_OFF   = ABUF_OFF + 256;                      // 256
static constexpr size_t CWA_OFF    = BBUF_OFF + 256;                      // 256
static constexpr size_t C0_OFF     = CWA_OFF + 256;                       // 256
static constexpr size_t CELL256_OFF = C0_OFF + 256;                       // BB*NP ints
static constexpr size_t CELL64_OFF  = CELL256_OFF + (size_t)BB * NP;      // BB*NP ints
static constexpr size_t DEN1_OFF   = CELL64_OFF + (size_t)BB * NP;        // BB*NTOK
static constexpr size_t DEN2_OFF   = DEN1_OFF + (size_t)BB * NTOK;        // BB*NS
static constexpr size_t STARTS_OFF = DEN2_OFF + (size_t)BB * NS;          // NSEG ints
static constexpr size_t BLKSUM_OFF = STARTS_OFF + NSEG;                   // 512 ints
static constexpr size_t BLKEXCL_OFF = BLKSUM_OFF + 512;                   // 512 ints
static constexpr size_t PIDX_OFF   = BLKEXCL_OFF + 512;                   // 3*BB*NP ints

// ---------------- helpers ----------------

__device__ __forceinline__ unsigned short f2bf(float f) {
    unsigned int u = __float_as_uint(f);
    return (unsigned short)((u + 0x7FFFu + ((u >> 16) & 1u)) >> 16);
}
__device__ __forceinline__ float bf2f(unsigned short u) {
    return __uint_as_float((unsigned int)u << 16);
}

// ---------------- kernels ----------------

// grid cell indices for both grids (RNE via rintf) + CSR histogram, fused
__global__ void k_cellhist(const float* __restrict__ loc, const int* __restrict__ idx_agg,
                           int* __restrict__ cell256, int* __restrict__ cell64,
                           int* __restrict__ cnts) {
    int i = blockIdx.x * 256 + threadIdx.x;   // over BB*NP
    int b = i >> 16;
    float lx = fminf(fmaxf(loc[2 * (size_t)i], -1.f), 1.f);
    float ly = fminf(fmaxf(loc[2 * (size_t)i + 1], -1.f), 1.f);
    int px = (int)rintf(0.5f * (lx + 1.f) * WM - 0.5f);
    px = min(max(px, 0), WM - 1);
    int py = (int)rintf(0.5f * (ly + 1.f) * HM - 0.5f);
    py = min(max(py, 0), HM - 1);
    int c256 = py * WM + px;
    cell256[i] = c256;
    int qx = (int)rintf(0.5f * (lx + 1.f) * WC - 0.5f);
    qx = min(max(qx, 0), WC - 1);
    int qy = (int)rintf(0.5f * (ly + 1.f) * HC - 0.5f);
    qy = min(max(qy, 0), HC - 1);
    int c64 = qy * WC + qx;
    cell64[i] = c64;
    atomicAdd(&cnts[b * NP + c256], 1);
    atomicAdd(&cnts[SEG_TOK + b * NTOK + idx_agg[i]], 1);
    atomicAdd(&cnts[SEG_64 + b * NS + c64], 1);
}

// cast x to bf16 once (random-gather source)
__global__ void k_xcast(const float* __restrict__ x, unsigned short* __restrict__ xbf) {
    size_t i = (size_t)blockIdx.x * 256 + threadIdx.x;  // float4 groups
    float4 v = ((const float4*)x)[i];
    ushort4 o;
    o.x = f2bf(v.x); o.y = f2bf(v.y); o.z = f2bf(v.z); o.w = f2bf(v.w);
    ((ushort4*)xbf)[i] = o;
}

// 2-level exclusive scan over NSEG = 336*1024 counters
__global__ __launch_bounds__(256) void k_scan1(const int* __restrict__ cnts,
                                               int* __restrict__ starts,
                                               int* __restrict__ blksum) {
    int t = threadIdx.x;
    int base = blockIdx.x * 1024 + t * 4;
    int4 v = *(const int4*)(cnts + base);
    int tsum = v.x + v.y + v.z + v.w;
    __shared__ int s[256];
    s[t] = tsum;
    __syncthreads();
    for (int off = 1; off < 256; off <<= 1) {
        int add = (t >= off) ? s[t - off] : 0;
        __syncthreads();
        s[t] += add;
        __syncthreads();
    }
    int excl = s[t] - tsum;
    int4 o;
    o.x = excl; o.y = excl + v.x; o.z = o.y + v.y; o.w = o.z + v.z;
    *(int4*)(starts + base) = o;
    if (t == 255) blksum[blockIdx.x] = s[255];
}

__global__ __launch_bounds__(512) void k_scan2(const int* __restrict__ blksum,
                                               int* __restrict__ blkexcl) {
    int t = threadIdx.x;
    __shared__ int s[512];
    int v = (t < 336) ? blksum[t] : 0;
    s[t] = v;
    __syncthreads();
    for (int off = 1; off < 512; off <<= 1) {
        int add = (t >= off) ? s[t - off] : 0;
        __syncthreads();
        s[t] += add;
        __syncthreads();
    }
    if (t < 336) blkexcl[t] = s[t] - v;
}

// fill CSR pools: map stores resolved token id, tok stores point id, cell64 stores token id
__global__ void k_fill(const int* __restrict__ cell256, const int* __restrict__ idx_agg,
                       const int* __restrict__ cell64, const int* __restrict__ starts,
                       const int* __restrict__ blkexcl, int* __restrict__ curs,
                       int* __restrict__ pidx) {
    int gp = blockIdx.x * 256 + threadIdx.x;  // over BB*NP
    int b = gp >> 16;
    int ia = idx_agg[gp];
    int t1 = b * NP + cell256[gp];
    int p1 = starts[t1] + blkexcl[t1 >> 10] + atomicAdd(&curs[t1], 1);
    pidx[p1] = ia;
    int t2 = SEG_TOK + b * NTOK + ia;
    int p2 = starts[t2] + blkexcl[t2 >> 10] + atomicAdd(&curs[t2], 1);
    pidx[p2] = gp;
    int t3 = SEG_64 + b * NS + cell64[gp];
    int p3 = starts[t3] + blkexcl[t3 >> 10] + atomicAdd(&curs[t3], 1);
    pidx[p3] = ia;
}

// token2map as gather: per map cell, sum bf16 token rows, normalize, write bf16
__global__ __launch_bounds__(256) void k_gather_map(const unsigned short* __restrict__ xbf,
                                                    const int* __restrict__ starts,
                                                    const int* __restrict__ blkexcl,
                                                    const int* __restrict__ cnts,
                                                    const int* __restrict__ pidx,
                                                    unsigned short* __restrict__ xmapn) {
    int tgt = blockIdx.x * 8 + (threadIdx.x >> 5);  // over BB*NP
    int lane = threadIdx.x & 31;                    // 32 lanes x 4ch = 128 ch
    int b = tgt >> 16;
    int start = starts[tgt] + blkexcl[tgt >> 10];
    int cnt = cnts[tgt];
    float4 acc = make_float4(0.f, 0.f, 0.f, 0.f);
    for (int j = 0; j < cnt; ++j) {
        int tk = pidx[start + j];
        ushort4 u = *(const ushort4*)(xbf + ((size_t)b * NTOK + tk) * CIN + lane * 4);
        acc.x += bf2f(u.x); acc.y += bf2f(u.y); acc.z += bf2f(u.z); acc.w += bf2f(u.w);
    }
    float inv = 1.0f / ((float)cnt + EPS);
    ushort4 o;
    o.x = f2bf(acc.x * inv);
    o.y = f2bf(acc.y * inv);
    o.z = f2bf(acc.z * inv);
    o.w = f2bf(acc.w * inv);
    *(ushort4*)(xmapn + (size_t)tgt * CIN + lane * 4) = o;
}

// pre-swizzle conv weights into MFMA 16x16x32 B-fragment lane layout
__global__ void k_wfrag(const float* __restrict__ cw, unsigned short* __restrict__ wfrag) {
    int i = blockIdx.x * 256 + threadIdx.x;  // over 9*4*16*512
    int j = i & 7;
    int lane = (i >> 3) & 63;
    int nt = (i >> 9) & 15;
    int kc = (i >> 13) & 3;
    int khw = i >> 15;
    int c = kc * 32 + ((lane >> 4) << 3) + j;
    int n = nt * 16 + (lane & 15);
    wfrag[i] = f2bf(cw[((size_t)khw * CIN + c) * COUT + n]);
}

// pre-swizzle skip weights (COUT x CIN, row-major) into same B-fragment layout
__global__ void k_sfrag(const float* __restrict__ sw, unsigned short* __restrict__ sfrag) {
    int i = blockIdx.x * 256 + threadIdx.x;  // over 4*16*512
    int j = i & 7;
    int lane = (i >> 3) & 63;
    int nt = (i >> 9) & 15;
    int kc = i >> 13;
    int c = kc * 32 + ((lane >> 4) << 3) + j;
    int n = nt * 16 + (lane & 15);
    sfrag[i] = f2bf(sw[(size_t)n * CIN + c]);
}

// 3x3 stride-2 pad-1 conv as implicit GEMM on bf16 MFMA 16x16x32; bf16 output.
__global__ __launch_bounds__(256) void k_convmf(const unsigned short* __restrict__ xmapn,
                                                const unsigned short* __restrict__ wfrag,
                                                const float* __restrict__ cb,
                                                unsigned short* __restrict__ y) {
    int bz = blockIdx.x;
    int ow0 = (bz & 1) * 64;
    int oh = (bz >> 1) & (HD - 1);
    int b = bz >> 8;
    int tid = threadIdx.x;
    int w = tid >> 6, lane = tid & 63;
    int n0 = w * 64;

    __shared__ unsigned short s_even[65 * 136];
    __shared__ unsigned short s_odd[64 * 136];

    ffrag4 acc[4][4];
#pragma unroll
    for (int mt = 0; mt < 4; ++mt)
#pragma unroll
        for (int nt = 0; nt < 4; ++nt) {
            ffrag4 z = {0.f, 0.f, 0.f, 0.f};
            acc[mt][nt] = z;
        }

    int iw0 = 2 * ow0 - 1;
    int lm = lane & 15;
    int lq = lane >> 4;
    int cbase = lq << 3;

    for (int kh = 0; kh < 3; ++kh) {
        int ih = 2 * oh - 1 + kh;
        __syncthreads();
        {
            const unsigned short* rowb =
                xmapn + ((size_t)b * NP + (size_t)ih * WM) * CIN;
            bool ihok = (ih >= 0 && ih < HM);
            for (int idx = tid; idx < 129 * 16; idx += 256) {
                int pix = idx >> 4;
                int c8 = (idx & 15) * 8;
                int iw = iw0 + pix;
                uint4 v = make_uint4(0u, 0u, 0u, 0u);
                if (ihok && iw >= 0 && iw < WM)
                    v = *(const uint4*)(rowb + (size_t)iw * CIN + c8);
                unsigned short* dst = (pix & 1)
                    ? &s_odd[(size_t)((pix - 1) >> 1) * 136 + c8]
                    : &s_even[(size_t)(pix >> 1) * 136 + c8];
                *(uint4*)dst = v;
            }
        }
        __syncthreads();
#pragma unroll
        for (int kw = 0; kw < 3; ++kw) {
            int khw = kh * 3 + kw;
#pragma unroll
            for (int kc = 0; kc < 4; ++kc) {
                int c = kc * 32 + cbase;
                bfrag8 af[4];
#pragma unroll
                for (int mt = 0; mt < 4; ++mt) {
                    int m = mt * 16 + lm;
                    const unsigned short* src;
                    if (kw == 1)      src = &s_odd[(size_t)m * 136 + c];
                    else if (kw == 0) src = &s_even[(size_t)m * 136 + c];
                    else              src = &s_even[(size_t)(m + 1) * 136 + c];
                    af[mt] = *(const bfrag8*)(const void*)src;
                }
                const unsigned short* wb =
                    wfrag + ((size_t)((khw * 4 + kc) * 16) + w * 4) * 512 + lane * 8;
#pragma unroll
                for (int nt = 0; nt < 4; ++nt) {
                    bfrag8 bf = *(const bfrag8*)(const void*)(wb + (size_t)nt * 512);
#pragma unroll
                    for (int mt = 0; mt < 4; ++mt)
                        acc[mt][nt] = __builtin_amdgcn_mfma_f32_16x16x32_bf16(
                            af[mt], bf, acc[mt][nt], 0, 0, 0);
                }
            }
        }
    }

    unsigned short* yb = y + (((size_t)b * HD + oh) * WD + ow0) * COUT;
#pragma unroll
    for (int nt = 0; nt < 4; ++nt) {
        int n = n0 + nt * 16 + lm;
        float bias = cb[n];
#pragma unroll
        for (int mt = 0; mt < 4; ++mt) {
#pragma unroll
            for (int r = 0; r < 4; ++r) {
                int m = mt * 16 + lq * 4 + r;
                yb[(size_t)m * COUT + n] = f2bf(acc[mt][nt][r] + bias);
            }
        }
    }
}

// map2token as gather: per token (one wave), bilinear-sample its points from bf16 y,
// direct write raw num + den1 (1 token/wave: oversubscription absorbs cnt variance)
__global__ __launch_bounds__(256) void k_gather_tok(const unsigned short* __restrict__ y,
                                                    const float* __restrict__ loc,
                                                    const float* __restrict__ aggw,
                                                    const int* __restrict__ starts,
                                                    const int* __restrict__ blkexcl,
                                                    const int* __restrict__ cnts,
                                                    const int* __restrict__ pidx,
                                                    float* __restrict__ num_out,
                                                    float* __restrict__ den1) {
    int wv = threadIdx.x >> 6, lane = threadIdx.x & 63;  // 64 lanes x 4ch = 256 ch
    int tl = blockIdx.x * 4 + wv;                        // over BB*NTOK
    int b = tl >> 14;
    int tgt = SEG_TOK + tl;
    int start = starts[tgt] + blkexcl[tgt >> 10];
    int cnt = cnts[tgt];
    const unsigned short* ybase = y + (size_t)b * (HD * WD * COUT);
    float4 num = make_float4(0.f, 0.f, 0.f, 0.f);
    float den = 0.f;
    for (int j = 0; j < cnt; ++j) {
        int gp = pidx[start + j];
        float lx = fminf(fmaxf(loc[2 * (size_t)gp], -1.f), 1.f);
        float ly = fminf(fmaxf(loc[2 * (size_t)gp + 1], -1.f), 1.f);
        float fx = fminf(fmaxf(0.5f * (lx + 1.f) * WD - 0.5f, 0.f), (float)(WD - 1));
        float fy = fminf(fmaxf(0.5f * (ly + 1.f) * HD - 0.5f, 0.f), (float)(HD - 1));
        float x0f = floorf(fx), y0f = floorf(fy);
        float wx = fx - x0f, wy = fy - y0f;
        int x0 = (int)x0f, y0 = (int)y0f;
        int x1 = min(x0 + 1, WD - 1), y1 = min(y0 + 1, HD - 1);
        ushort4 u00 = *(const ushort4*)(ybase + ((size_t)y0 * WD + x0) * COUT + lane * 4);
        ushort4 u01 = *(const ushort4*)(ybase + ((size_t)y0 * WD + x1) * COUT + lane * 4);
        ushort4 u10 = *(const ushort4*)(ybase + ((size_t)y1 * WD + x0) * COUT + lane * 4);
        ushort4 u11 = *(const ushort4*)(ybase + ((size_t)y1 * WD + x1) * COUT + lane * 4);
        float w00 = (1.f - wx) * (1.f - wy), w01 = wx * (1.f - wy);
        float w10 = (1.f - wx) * wy, w11 = wx * wy;
        float aw = aggw[gp];
        num.x += (w00 * bf2f(u00.x) + w01 * bf2f(u01.x) + w10 * bf2f(u10.x) + w11 * bf2f(u11.x)) * aw;
        num.y += (w00 * bf2f(u00.y) + w01 * bf2f(u01.y) + w10 * bf2f(u10.y) + w11 * bf2f(u11.y)) * aw;
        num.z += (w00 * bf2f(u00.z) + w01 * bf2f(u01.z) + w10 * bf2f(u10.z) + w11 * bf2f(u11.z)) * aw;
        num.w += (w00 * bf2f(u00.w) + w01 * bf2f(u01.w) + w10 * bf2f(u10.w) + w11 * bf2f(u11.w)) * aw;
        den += aw;
    }
    *(float4*)(num_out + (size_t)tl * COUT + lane * 4) = num;
    if (lane == 0) den1[tl] = den;
}

// tok = num/(den1+eps) + x @ skip_w^T via MFMA (in place over out_x region),
// with BN sum/sumsq fused into the epilogue (quad shuffle-reduce + atomics)
__global__ __launch_bounds__(256) void k_tokmf(const unsigned short* __restrict__ xbf,
                                               const unsigned short* __restrict__ sfrag,
                                               const float* __restrict__ den1,
                                               float* __restrict__ tok,
                                               float* __restrict__ bnsum,
                                               float* __restrict__ bnsq) {
    int t0 = blockIdx.x * 64;   // grid = BB*NTOK/64
    int tid = threadIdx.x;
    int w = tid >> 6, lane = tid & 63;
    int n0 = w * 64;
    int lm = lane & 15, lq = lane >> 4;

    __shared__ unsigned short s_x[64 * 136];
    const unsigned short* xb = xbf + (size_t)t0 * CIN;
    for (int idx = tid; idx < 64 * 16; idx += 256) {
        int row = idx >> 4, c8 = (idx & 15) * 8;
        *(uint4*)&s_x[(size_t)row * 136 + c8] = *(const uint4*)(xb + (size_t)row * CIN + c8);
    }
    __syncthreads();

    ffrag4 acc[4][4];
#pragma unroll
    for (int mt = 0; mt < 4; ++mt)
#pragma unroll
        for (int nt = 0; nt < 4; ++nt) {
            ffrag4 z = {0.f, 0.f, 0.f, 0.f};
            acc[mt][nt] = z;
        }

#pragma unroll
    for (int kc = 0; kc < 4; ++kc) {
        int c = kc * 32 + lq * 8;
        bfrag8 af[4];
#pragma unroll
        for (int mt = 0; mt < 4; ++mt)
            af[mt] = *(const bfrag8*)(const void*)&s_x[(size_t)(mt * 16 + lm) * 136 + c];
        const unsigned short* sb = sfrag + ((size_t)(kc * 16) + w * 4) * 512 + lane * 8;
#pragma unroll
        for (int nt = 0; nt < 4; ++nt) {
            bfrag8 bf = *(const bfrag8*)(const void*)(sb + (size_t)nt * 512);
#pragma unroll
            for (int mt = 0; mt < 4; ++mt)
                acc[mt][nt] = __builtin_amdgcn_mfma_f32_16x16x32_bf16(
                    af[mt], bf, acc[mt][nt], 0, 0, 0);
        }
    }

    float bsum[4] = {0.f, 0.f, 0.f, 0.f};
    float bsq[4] = {0.f, 0.f, 0.f, 0.f};
#pragma unroll
    for (int mt = 0; mt < 4; ++mt) {
#pragma unroll
        for (int r = 0; r < 4; ++r) {
            int tkn = t0 + mt * 16 + lq * 4 + r;
            float inv = 1.f / (den1[tkn] + EPS);
#pragma unroll
            for (int nt = 0; nt < 4; ++nt) {
                int n = n0 + nt * 16 + lm;
                size_t a = (size_t)tkn * COUT + n;
                float v = tok[a] * inv + acc[mt][nt][r];
                tok[a] = v;
                bsum[nt] += v;
                bsq[nt] = fmaf(v, v, bsq[nt]);
            }
        }
    }
#pragma unroll
    for (int nt = 0; nt < 4; ++nt) {
        bsum[nt] += __shfl_down(bsum[nt], 32);
        bsq[nt] += __shfl_down(bsq[nt], 32);
        bsum[nt] += __shfl_down(bsum[nt], 16);
        bsq[nt] += __shfl_down(bsq[nt], 16);
    }
    if (lq == 0) {
#pragma unroll
        for (int nt = 0; nt < 4; ++nt) {
            int n = n0 + nt * 16 + lm;
            atomicAdd(&bnsum[n], bsum[nt]);
            atomicAdd(&bnsq[n], bsq[nt]);
        }
    }
}

// per-channel BN affine: a=gamma/sqrt(var+eps), bb=beta-mu*a; fold conf head
__global__ void k_bnparams(const float* __restrict__ bnsum, const float* __restrict__ bnsq,
                           const float* __restrict__ gamma, const float* __restrict__ beta,
                           const float* __restrict__ confw, const float* __restrict__ confb,
                           float* __restrict__ abuf, float* __restrict__ bbuf,
                           float* __restrict__ cwa, float* __restrict__ c0) {
    int k = threadIdx.x;
    const float cntv = (float)(BB * NTOK);
    float mu = bnsum[k] / cntv;
    float var = bnsq[k] / cntv - mu * mu;
    float a = gamma[k] * rsqrtf(var + BNEPS);
    float bbv = beta[k] - mu * a;
    abuf[k] = a;
    bbuf[k] = bbv;
    float cw = confw[k];
    cwa[k] = a * cw;
    __shared__ float red[256];
    red[k] = bbv * cw;
    __syncthreads();
    for (int s = 128; s > 0; s >>= 1) {
        if (k < s) red[k] += red[k + s];
        __syncthreads();
    }
    if (k == 0) c0[0] = red[0] + confb[0];
}

// conf = dot(tok, cwa) + c0; emit tokn bf16 (tokb), exp(conf) (wexp),
// and relu(tokn) in place over tok (out_x region)
__global__ void k_confrelu(float* __restrict__ tok, const float* __restrict__ cwa,
                           const float* __restrict__ c0v, const float* __restrict__ abuf,
                           const float* __restrict__ bbuf, float* __restrict__ conf_out,
                           unsigned short* __restrict__ tokb, float* __restrict__ wexp) {
    int tid = threadIdx.x;
    int tkn = blockIdx.x * 16 + (tid >> 4);
    int kc = (tid & 15) * 16;
    float* row = tok + (size_t)tkn * COUT + kc;
    unsigned short* tb = tokb + (size_t)tkn * COUT + kc;
    float s = 0.f;
#pragma unroll
    for (int i = 0; i < 16; i += 4) {
        float4 v = *(const float4*)(row + i);
        float4 w = *(const float4*)(cwa + kc + i);
        float4 a = *(const float4*)(abuf + kc + i);
        float4 bb = *(const float4*)(bbuf + kc + i);
        s += v.x * w.x + v.y * w.y + v.z * w.z + v.w * w.w;
        float4 tn;
        tn.x = fmaf(a.x, v.x, bb.x);
        tn.y = fmaf(a.y, v.y, bb.y);
        tn.z = fmaf(a.z, v.z, bb.z);
        tn.w = fmaf(a.w, v.w, bb.w);
        ushort4 o;
        o.x = f2bf(tn.x); o.y = f2bf(tn.y); o.z = f2bf(tn.z); o.w = f2bf(tn.w);
        *(ushort4*)(tb + i) = o;
        float4 rl;
        rl.x = fmaxf(tn.x, 0.f); rl.y = fmaxf(tn.y, 0.f);
        rl.z = fmaxf(tn.z, 0.f); rl.w = fmaxf(tn.w, 0.f);
        *(float4*)(row + i) = rl;
    }
    for (int off = 8; off > 0; off >>= 1) s += __shfl_down(s, off, 16);
    if ((tid & 15) == 0) {
        float cv = s + c0v[0];
        conf_out[tkn] = cv;
        wexp[tkn] = expf(cv);
    }
}

// cluster as gather over bf16 tokn rows + precomputed exp weights; fused relu epilogue
__global__ __launch_bounds__(256) void k_gather_cluster(const unsigned short* __restrict__ tokb,
                                                        const float* __restrict__ wexp,
                                                        const int* __restrict__ starts,
                                                        const int* __restrict__ blkexcl,
                                                        const int* __restrict__ cnts,
                                                        const int* __restrict__ pidx,
                                                        float* __restrict__ xdown,
                                                        float* __restrict__ den2) {
    int wv = threadIdx.x >> 6, lane = threadIdx.x & 63;  // 64 lanes x 4ch = 256 ch
    int tl = blockIdx.x * 4 + wv;                        // over BB*NS
    int b = tl >> 12;
    int tgt = SEG_64 + tl;
    int start = starts[tgt] + blkexcl[tgt >> 10];
    int cnt = cnts[tgt];
    float4 num = make_float4(0.f, 0.f, 0.f, 0.f);
    float den = 0.f;
    for (int j = 0; j < cnt; ++j) {
        int ia = pidx[start + j];
        float w = wexp[(size_t)b * NTOK + ia];
        ushort4 u = *(const ushort4*)(tokb + ((size_t)b * NTOK + ia) * COUT + lane * 4);
        num.x = fmaf(bf2f(u.x), w, num.x);
        num.y = fmaf(bf2f(u.y), w, num.y);
        num.z = fmaf(bf2f(u.z), w, num.z);
        num.w = fmaf(bf2f(u.w), w, num.w);
        den += w;
    }
    float inv = 1.f / (den + EPS);
    float4 o;
    o.x = fmaxf(num.x * inv, 0.f);
    o.y = fmaxf(num.y * inv, 0.f);
    o.z = fmaxf(num.z * inv, 0.f);
    o.w = fmaxf(num.w * inv, 0.f);
    *(float4*)(xdown + (size_t)tl * COUT + lane * 4) = o;
    if (lane == 0) den2[tl] = den;
}

// agg_weight_down numerator + per-batch max (positive floats -> uint atomicMax)
__global__ void k_awd1(const float* __restrict__ wexp, const float* __restrict__ den2,
                       const int* __restrict__ idx_agg, const int* __restrict__ cell64,
                       const float* __restrict__ aggw, float* __restrict__ awdt,
                       float* __restrict__ idx_out_f, unsigned int* __restrict__ maxw) {
    int b = blockIdx.x >> 6;
    int chunk = blockIdx.x & 63;
    int base = b * NP + chunk * 1024;
    float lmax = 0.f;
    for (int t = threadIdx.x; t < 1024; t += 256) {
        int gp = base + t;
        int ia = idx_agg[gp];
        int cell = cell64[gp];
        float w = wexp[(size_t)b * NTOK + ia];
        float wt = w / (den2[(size_t)b * NS + cell] + EPS);
        float tv = aggw[gp] * wt;
        awdt[gp] = tv;
        idx_out_f[gp] = (float)cell;
        lmax = fmaxf(lmax, tv);
    }
    __shared__ float red[256];
    red[threadIdx.x] = lmax;
    __syncthreads();
    for (int s = 128; s > 0; s >>= 1) {
        if (threadIdx.x < s) red[threadIdx.x] = fmaxf(red[threadIdx.x], red[threadIdx.x + s]);
        __syncthreads();
    }
    if (threadIdx.x == 0) atomicMax(maxw + b, __float_as_uint(red[0]));
}

__global__ void k_awd2(const float* __restrict__ awdt, const unsigned int* __restrict__ maxw,
                       float* __restrict__ awd_out) {
    int i = blockIdx.x * 256 + threadIdx.x;  // over BB*NP
    int b = i >> 16;
    awd_out[i] = awdt[i] / __uint_as_float(maxw[b]);
}

extern "C" void kernel_launch(void* const* d_in, const int* in_sizes, int n_in,
                              void* d_out, int out_size, void* d_ws, size_t ws_size,
                              hipStream_t stream) {
    const float* x        = (const float*)d_in[0];
    const float* loc      = (const float*)d_in[1];
    const int*   idx_agg  = (const int*)d_in[2];
    const float* aggw     = (const float*)d_in[3];
    const float* conv_w   = (const float*)d_in[4];
    const float* conv_b   = (const float*)d_in[5];
    const float* skip_w   = (const float*)d_in[6];
    const float* bn_gamma = (const float*)d_in[7];
    const float* bn_beta  = (const float*)d_in[8];
    const float* conf_w   = (const float*)d_in[9];
    const float* conf_b   = (const float*)d_in[10];

    float* ws      = (float*)d_ws;
    float* bnsum   = ws + BNSUM_OFF;
    float* bnsq    = ws + BNSQ_OFF;
    unsigned int* maxw = (unsigned int*)(ws + MAXW_OFF);
    int*   cnts    = (int*)(ws + CNTS_OFF);
    int*   curs    = (int*)(ws + CURS_OFF);
    unsigned short* ybuf  = (unsigned short*)(ws + YBUF_OFF);
    unsigned short* xmapn = (unsigned short*)(ws + XMAPN_OFF);
    unsigned short* xbf   = (unsigned short*)(ws + XBF_OFF);
    unsigned short* tokb  = (unsigned short*)(ws + TOKB_OFF);
    unsigned short* wfrag = (unsigned short*)(ws + WFRAG_OFF);
    unsigned short* sfrag = (unsigned short*)(ws + SFRAG_OFF);
    float* wexp    = ws + WEXP_OFF;
    float* awdt    = ws + AWDT_OFF;
    float* abuf    = ws + ABUF_OFF;
    float* bbuf    = ws + BBUF_OFF;
    float* cwa     = ws + CWA_OFF;
    float* c0      = ws + C0_OFF;
    int*   cell256 = (int*)(ws + CELL256_OFF);
    int*   cell64  = (int*)(ws + CELL64_OFF);
    float* den1    = ws + DEN1_OFF;
    float* den2    = ws + DEN2_OFF;
    int*   starts  = (int*)(ws + STARTS_OFF);
    int*   blksum  = (int*)(ws + BLKSUM_OFF);
    int*   blkexcl = (int*)(ws + BLKEXCL_OFF);
    int*   pidx    = (int*)(ws + PIDX_OFF);

    float* out       = (float*)d_out;
    float* out_xdown = out;                                    // [4,4096,256]
    float* out_x     = out + (size_t)BB * NS * COUT;           // [4,16384,256] (num -> tok -> relu(tokn))
    float* out_conf  = out_x + (size_t)BB * NTOK * COUT;       // [4,16384,1]
    float* out_awd   = out_conf + (size_t)BB * NTOK;           // [4,65536,1]
    float* out_idx   = out_awd + (size_t)BB * NP;              // [4,65536] written as float

    // zero the small accumulator region (ws is poisoned 0xAA every call)
    hipMemsetAsync(d_ws, 0, ZERO_FLOATS * sizeof(float), stream);

    k_xcast<<<BB * NTOK * CIN / 4 / 256, 256, 0, stream>>>(x, xbf);
    k_wfrag<<<9 * 4 * 16 * 512 / 256, 256, 0, stream>>>(conv_w, wfrag);
    k_sfrag<<<4 * 16 * 512 / 256, 256, 0, stream>>>(skip_w, sfrag);
    k_cellhist<<<BB * NP / 256, 256, 0, stream>>>(loc, idx_agg, cell256, cell64, cnts);
    k_scan1<<<NSEG / 1024, 256, 0, stream>>>(cnts, starts, blksum);
    k_scan2<<<1, 512, 0, stream>>>(blksum, blkexcl);
    k_fill<<<BB * NP / 256, 256, 0, stream>>>(cell256, idx_agg, cell64, starts,
                                              blkexcl, curs, pidx);
    k_gather_map<<<BB * NP / 8, 256, 0, stream>>>(xbf, starts, blkexcl, cnts, pidx, xmapn);
    k_convmf<<<BB * HD * 2, 256, 0, stream>>>(xmapn, wfrag, conv_b, ybuf);
    k_gather_tok<<<BB * NTOK / 4, 256, 0, stream>>>(ybuf, loc, aggw, starts, blkexcl,
                                                    cnts, pidx, out_x, den1);
    k_tokmf<<<BB * NTOK / 64, 256, 0, stream>>>(xbf, sfrag, den1, out_x, bnsum, bnsq);
    k_bnparams<<<1, 256, 0, stream>>>(bnsum, bnsq, bn_gamma, bn_beta, conf_w, conf_b,
                                      abuf, bbuf, cwa, c0);
    k_confrelu<<<BB * NTOK / 16, 256, 0, stream>>>(out_x, cwa, c0, abuf, bbuf,
                                                   out_conf, tokb, wexp);
    k_gather_cluster<<<BB * NS / 4, 256, 0, stream>>>(tokb, wexp, starts, blkexcl,
                                                      cnts, pidx, out_xdown, den2);
    k_awd1<<<BB * 64, 256, 0, stream>>>(wexp, den2, idx_agg, cell64, aggw,
                                        awdt, out_idx, maxw);
    k_awd2<<<BB * NP / 256, 256, 0, stream>>>(awdt, maxw, out_awd);
}